// Round 15
// baseline (523.696 us; speedup 1.0000x reference)
//
#include <hip/hip_runtime.h>
#include <hip/hip_bf16.h>

// SeqExperts: 64 experts, 128 tokens each, d_model=1024, d_hidden=4096.
// out[e*128+m] = relu(x_e @ W1[e]^T) @ W2[e]^T
// R12 (479, BEST): BK=64 dbuf counted-vmcnt, chunk-XOR swizzle, pack2,
//      inline fp32->bf16 A-staging, XCD swizzle, no nontemporal.
// R13 (523 FAIL) K-rotation. R14 (485 ~flat) dense staging -> reverted.
// R15: pass2 tile M=64xN=128 (K-pipeline identical). LDS 48 KB -> 3 blocks/CU
//      (__launch_bounds__(256,3)), grid 1024 -> breaks the single-generation
//      quantization of pass2 (512 blocks = exactly 2/CU had zero scheduler
//      slack). M-halves of an (e,nt) adjacent -> W2 slab L2-shared. Pass1
//      byte-identical to R12.

typedef __attribute__((ext_vector_type(8))) short bf16x8;   // 8 bf16 (4 VGPRs)
typedef __attribute__((ext_vector_type(4))) float f32x4;
typedef __attribute__((ext_vector_type(4))) unsigned int u32x4;

#define N_EXPERTS 64
#define DM 1024
#define DH 4096
#define TOKS 128

__device__ __forceinline__ unsigned f2u(float f) {
    union { float f; unsigned u; } v; v.f = f; return v.u;
}
// round-half-up fp32->bf16 (0.5 ulp; no NaN/inf in data)
__device__ __forceinline__ unsigned short f2bf(float f) {
    return (unsigned short)((f2u(f) + 0x8000u) >> 16);
}
// pack two fp32 -> 2xbf16 in one u32
__device__ __forceinline__ unsigned pack2(float lo, float hi) {
    return ((f2u(lo) + 0x8000u) >> 16) | ((f2u(hi) + 0x8000u) & 0xFFFF0000u);
}

// C[MROWS x 128-col-tile] = A[MROWS x K] * B[128 x K]^T for expert e.
// A: fp32 (pass1 x) or bf16 (pass2 h), row-major lda=K. B: fp32 weights [N][K].
// C: bf16+relu (pass1) or fp32 (pass2).
// LDS A[2][MROWS][64] + B[2][128][64] bf16; 16B chunks XOR-swizzled:
// chunk c stored at c^((row>>1)&7); read offset (kq{+4})^((lrow>>1)&7).
// MTILES = TOKS/MROWS; work id = ((e*NTILES + nt)*MTILES + mt).
template<int N, int K, int MROWS, bool A_BF16, bool RELU_OUT_BF16, int MINW>
__global__ __launch_bounds__(256, MINW)
void moe_gemm(const void* __restrict__ Ap, const float* __restrict__ Bp,
              void* __restrict__ Cp, int nwg_per_xcd)
{
    constexpr int BK = 64;
    constexpr int NT = K / BK;          // 16 (pass1) / 64 (pass2); even
    constexpr int NTILES = N / 128;
    constexpr int MTILES = TOKS / MROWS;
    constexpr int AJ = MROWS / 32;      // A staging row-groups (4 or 2)
    constexpr int AI = MROWS / 32;      // acc row-frags per wave (4 or 2)

    __shared__ unsigned short sA[2][MROWS][BK];
    __shared__ unsigned short sB[2][128][BK];

    const int tid = threadIdx.x;
    const int bid = (blockIdx.x & 7) * nwg_per_xcd + (blockIdx.x >> 3);
    const int e   = bid / (NTILES * MTILES);
    const int rem = bid % (NTILES * MTILES);
    const int nt  = rem / MTILES;
    const int mt  = rem % MTILES;

    const int lane = tid & 63;
    const int w    = tid >> 6;       // wave 0..3
    const int wr   = w >> 1;         // row half
    const int wc   = w & 1;          // col half
    const int lrow = lane & 15;
    const int kq   = lane >> 4;      // 0..3

    // staging: arow = tid>>3 (0..31; rows +j*32), ac = tid&7 (16B bf16 chunk).
    // Coalesced: 8 lanes cover a row's full 128B bf16 / 256B fp32 contiguously.
    const int arow = tid >> 3;
    const int ac   = tid & 7;
    const int swz  = (arow >> 1) & 7;    // +j*32 preserves (>>1)&7

    const unsigned short* aBaseH = nullptr;
    const float*          aBaseF = nullptr;
    if constexpr (A_BF16)
        aBaseH = (const unsigned short*)Ap + (size_t)(e * TOKS + mt * MROWS + arow) * K + ac * 8;
    else
        aBaseF = (const float*)Ap + (size_t)(e * TOKS + mt * MROWS + arow) * K + ac * 8;

    const float* bBase = Bp + ((size_t)e * N + (size_t)nt * 128 + arow) * K + ac * 8;

    const int sl = (lrow >> 1) & 7;
    const int offk0 = ((kq + 0) ^ sl) * 8;
    const int offk1 = ((kq + 4) ^ sl) * 8;

    f32x4 acc[AI][4];
    #pragma unroll
    for (int i = 0; i < AI; ++i)
        #pragma unroll
        for (int n = 0; n < 4; ++n)
            #pragma unroll
            for (int q = 0; q < 4; ++q) acc[i][n][q] = 0.f;

    struct Regs {
        u32x4 ah[AJ];  // A bf16: AJ x 16B chunks (rows +j*32)     [A_BF16]
        f32x4 af[2*AJ];// A fp32: AJ rows x 2 float4                [!A_BF16]
        f32x4 b[8];    // B fp32: 4 rows x 2 float4
    };
    Regs r0, r1;

    auto LOAD = [&](int t, Regs& r) {
        if constexpr (A_BF16) {
            #pragma unroll
            for (int j = 0; j < AJ; ++j)
                r.ah[j] = *(const u32x4*)(aBaseH + (size_t)j * 32 * K + t * BK);
        } else {
            #pragma unroll
            for (int j = 0; j < AJ; ++j) {
                const f32x4* p = (const f32x4*)(aBaseF + (size_t)j * 32 * K + t * BK);
                r.af[2 * j]     = p[0];
                r.af[2 * j + 1] = p[1];
            }
        }
        #pragma unroll
        for (int j = 0; j < 4; ++j) {
            const f32x4* p = (const f32x4*)(bBase + (size_t)j * 32 * K + t * BK);
            r.b[2 * j]     = p[0];
            r.b[2 * j + 1] = p[1];
        }
    };

    auto WRITE = [&](int buf, Regs& r) {
        const int c8 = (ac ^ swz) * 8;
        if constexpr (A_BF16) {
            #pragma unroll
            for (int j = 0; j < AJ; ++j)
                *(u32x4*)&sA[buf][arow + j * 32][c8] = r.ah[j];
        } else {
            #pragma unroll
            for (int j = 0; j < AJ; ++j) {
                f32x4 lo = r.af[2 * j], hi = r.af[2 * j + 1];
                u32x4 u = { pack2(lo[0], lo[1]), pack2(lo[2], lo[3]),
                            pack2(hi[0], hi[1]), pack2(hi[2], hi[3]) };
                *(u32x4*)&sA[buf][arow + j * 32][c8] = u;
            }
        }
        #pragma unroll
        for (int j = 0; j < 4; ++j) {
            f32x4 lo = r.b[2 * j], hi = r.b[2 * j + 1];
            u32x4 u = { pack2(lo[0], lo[1]), pack2(lo[2], lo[3]),
                        pack2(hi[0], hi[1]), pack2(hi[2], hi[3]) };
            *(u32x4*)&sB[buf][arow + j * 32][c8] = u;
        }
    };

    auto COMPUTE = [&](int buf) {
        #pragma unroll
        for (int kh = 0; kh < 2; ++kh) {
            const int off = kh ? offk1 : offk0;
            bf16x8 af[AI], bfr[4];
            #pragma unroll
            for (int i = 0; i < AI; ++i)
                af[i] = *(const bf16x8*)&sA[buf][wr * (MROWS / 2) + i * 16 + lrow][off];
            #pragma unroll
            for (int n = 0; n < 4; ++n)
                bfr[n] = *(const bf16x8*)&sB[buf][wc * 64 + n * 16 + lrow][off];
            #pragma unroll
            for (int i = 0; i < AI; ++i)
                #pragma unroll
                for (int n = 0; n < 4; ++n)
                    acc[i][n] = __builtin_amdgcn_mfma_f32_16x16x32_bf16(af[i], bfr[n], acc[i][n], 0, 0, 0);
        }
    };

    // Prologue: 2 tiles in flight.
    LOAD(0, r0);
    LOAD(1, r1);
    WRITE(0, r0);                          // counted vmcnt: waits only set 0
    asm volatile("s_waitcnt lgkmcnt(0)" ::: "memory");
    __builtin_amdgcn_s_barrier();

    for (int t = 0; t < NT; t += 2) {
        if (t + 2 < NT) LOAD(t + 2, r0);
        COMPUTE(0);
        if (t + 1 < NT) WRITE(1, r1);      // r0's newer loads stay in flight
        asm volatile("s_waitcnt lgkmcnt(0)" ::: "memory");
        __builtin_amdgcn_s_barrier();

        if (t + 3 < NT) LOAD(t + 3, r1);
        COMPUTE(1);
        if (t + 2 < NT) WRITE(0, r0);
        asm volatile("s_waitcnt lgkmcnt(0)" ::: "memory");
        __builtin_amdgcn_s_barrier();
    }

    // Epilogue. C/D layout (m89-verified): col = lane&15, row = (lane>>4)*4 + reg
    const size_t crow0 = (size_t)e * TOKS + (size_t)mt * MROWS;
    if constexpr (RELU_OUT_BF16) {
        unsigned short* C = (unsigned short*)Cp;
        #pragma unroll
        for (int i = 0; i < AI; ++i)
            #pragma unroll
            for (int n = 0; n < 4; ++n)
                #pragma unroll
                for (int q = 0; q < 4; ++q) {
                    const int row = wr * (MROWS / 2) + i * 16 + kq * 4 + q;
                    const int col = nt * 128 + wc * 64 + n * 16 + lrow;
                    C[(crow0 + row) * N + col] = f2bf(fmaxf(acc[i][n][q], 0.f));
                }
    } else {
        float* C = (float*)Cp;
        #pragma unroll
        for (int i = 0; i < AI; ++i)
            #pragma unroll
            for (int n = 0; n < 4; ++n)
                #pragma unroll
                for (int q = 0; q < 4; ++q) {
                    const int row = wr * (MROWS / 2) + i * 16 + kq * 4 + q;
                    const int col = nt * 128 + wc * 64 + n * 16 + lrow;
                    C[(crow0 + row) * N + col] = acc[i][n][q];
                }
    }
}

extern "C" void kernel_launch(void* const* d_in, const int* in_sizes, int n_in,
                              void* d_out, int out_size, void* d_ws, size_t ws_size,
                              hipStream_t stream) {
    const float* inputs = (const float*)d_in[0];   // [8192, 1024] fp32
    const float* w1     = (const float*)d_in[1];   // [64, 4096, 1024] fp32
    const float* w2     = (const float*)d_in[2];   // [64, 1024, 4096] fp32
    // d_in[3] = splits (always 128) -- unused

    unsigned short* h = (unsigned short*)d_ws;     // [8192, 4096] bf16 = 64 MiB
    float* out = (float*)d_out;                    // [8192, 1024] fp32

    // Pass 1: h = relu(x @ w1^T), bf16; M=128 tile (R12-identical). grid = 2048
    moe_gemm<DH, DM, 128, false, true, 2>
        <<<dim3(N_EXPERTS * (DH / 128)), dim3(256), 0, stream>>>(
        inputs, w1, h, N_EXPERTS * (DH / 128) / 8);
    // Pass 2: out = h @ w2^T, fp32; M=64 tile, 3 blocks/CU. grid = 64*8*2 = 1024
    moe_gemm<DM, DH, 64, true, false, 3>
        <<<dim3(N_EXPERTS * (DM / 128) * 2), dim3(256), 0, stream>>>(
        h, w2, out, N_EXPERTS * (DM / 128) * 2 / 8);
}

// Round 16
// 478.490 us; speedup vs baseline: 1.0945x; 1.0945x over previous
//
#include <hip/hip_runtime.h>
#include <hip/hip_bf16.h>

// SeqExperts: 64 experts, 128 tokens each, d_model=1024, d_hidden=4096.
// out[e*128+m] = relu(x_e @ W1[e]^T) @ W2[e]^T
// FINAL = R12 (479us, best): two-pass grouped GEMM, bf16 MFMA 16x16x32,
//   128x128 tile, BK=64 double-buffered LDS with counted-vmcnt pipeline,
//   chunk-XOR LDS swizzle, pack2 fp32->bf16 staging, XCD-aware block swizzle,
//   inline fp32->bf16 A-staging (no prepass), no nontemporal hints.
// Exonerated/regressed alternatives: no-LDS(794), fused+gating(694),
//   single-buffer(646), tileN-shrink(622), K-rotation(523), depth-3(529),
//   512thr(526), dense staging(485), tileM-shrink(524).
// Effective BW ~4.9 TB/s = ~78% of achievable 6.3; traffic is irreducible
// (2.15 GB fp32 weights read once).

typedef __attribute__((ext_vector_type(8))) short bf16x8;   // 8 bf16 (4 VGPRs)
typedef __attribute__((ext_vector_type(4))) float f32x4;
typedef __attribute__((ext_vector_type(4))) unsigned int u32x4;

#define N_EXPERTS 64
#define DM 1024
#define DH 4096
#define TOKS 128

__device__ __forceinline__ unsigned f2u(float f) {
    union { float f; unsigned u; } v; v.f = f; return v.u;
}
// round-half-up fp32->bf16 (0.5 ulp; no NaN/inf in data)
__device__ __forceinline__ unsigned short f2bf(float f) {
    return (unsigned short)((f2u(f) + 0x8000u) >> 16);
}
// pack two fp32 -> 2xbf16 in one u32
__device__ __forceinline__ unsigned pack2(float lo, float hi) {
    return ((f2u(lo) + 0x8000u) >> 16) | ((f2u(hi) + 0x8000u) & 0xFFFF0000u);
}

// C[128 x N] = A[128 x K] * B[N x K]^T for expert e.
// A: fp32 (pass1 x) or bf16 (pass2 h), row-major lda=K. B: fp32 weights [N][K].
// C: bf16+relu (pass1) or fp32 (pass2).
// LDS tiles [128][64] bf16 double-buffered; 16B chunks XOR-swizzled:
// chunk c stored at c^((row>>1)&7); read offset (kq{+4})^((lrow>>1)&7).
template<int N, int K, bool A_BF16, bool RELU_OUT_BF16>
__global__ __launch_bounds__(256, 2)
void moe_gemm(const void* __restrict__ Ap, const float* __restrict__ Bp,
              void* __restrict__ Cp, int nwg_per_xcd)
{
    constexpr int BK = 64;
    constexpr int NT = K / BK;      // 16 (pass1) / 64 (pass2); even
    constexpr int NTILES = N / 128;

    __shared__ unsigned short sA[2][128][BK];  // 16 KiB per buf
    __shared__ unsigned short sB[2][128][BK];

    const int tid = threadIdx.x;
    const int bid = (blockIdx.x & 7) * nwg_per_xcd + (blockIdx.x >> 3);
    const int e   = bid / NTILES;
    const int nt  = bid % NTILES;

    const int lane = tid & 63;
    const int w    = tid >> 6;       // wave 0..3
    const int wr   = w >> 1;
    const int wc   = w & 1;
    const int lrow = lane & 15;
    const int kq   = lane >> 4;      // 0..3

    // staging: arow = tid>>3 (0..31; rows +j*32), ac = tid&7 (16B bf16 chunk).
    // Coalesced: 8 lanes cover a row's full 128B bf16 / 256B fp32 contiguously.
    const int arow = tid >> 3;
    const int ac   = tid & 7;
    const int swz  = (arow >> 1) & 7;    // +j*32 preserves (>>1)&7

    const unsigned short* aBaseH = nullptr;
    const float*          aBaseF = nullptr;
    if constexpr (A_BF16)
        aBaseH = (const unsigned short*)Ap + (size_t)(e * TOKS + arow) * K + ac * 8;
    else
        aBaseF = (const float*)Ap + (size_t)(e * TOKS + arow) * K + ac * 8;

    const float* bBase = Bp + ((size_t)e * N + (size_t)nt * 128 + arow) * K + ac * 8;

    const int sl = (lrow >> 1) & 7;
    const int offk0 = ((kq + 0) ^ sl) * 8;
    const int offk1 = ((kq + 4) ^ sl) * 8;

    f32x4 acc[4][4];
    #pragma unroll
    for (int i = 0; i < 4; ++i)
        #pragma unroll
        for (int n = 0; n < 4; ++n)
            #pragma unroll
            for (int q = 0; q < 4; ++q) acc[i][n][q] = 0.f;

    struct Regs {
        u32x4 ah[4];   // A bf16: 4 x 16B chunks (rows j*32)       [A_BF16]
        f32x4 af[8];   // A fp32: 4 rows x 2 float4                 [!A_BF16]
        f32x4 b[8];    // B fp32: 4 rows x 2 float4
    };
    Regs r0, r1;

    auto LOAD = [&](int t, Regs& r) {
        if constexpr (A_BF16) {
            #pragma unroll
            for (int j = 0; j < 4; ++j)
                r.ah[j] = *(const u32x4*)(aBaseH + (size_t)j * 32 * K + t * BK);
        } else {
            #pragma unroll
            for (int j = 0; j < 4; ++j) {
                const f32x4* p = (const f32x4*)(aBaseF + (size_t)j * 32 * K + t * BK);
                r.af[2 * j]     = p[0];
                r.af[2 * j + 1] = p[1];
            }
        }
        #pragma unroll
        for (int j = 0; j < 4; ++j) {
            const f32x4* p = (const f32x4*)(bBase + (size_t)j * 32 * K + t * BK);
            r.b[2 * j]     = p[0];
            r.b[2 * j + 1] = p[1];
        }
    };

    auto WRITE = [&](int buf, Regs& r) {
        const int c8 = (ac ^ swz) * 8;
        if constexpr (A_BF16) {
            #pragma unroll
            for (int j = 0; j < 4; ++j)
                *(u32x4*)&sA[buf][arow + j * 32][c8] = r.ah[j];
        } else {
            #pragma unroll
            for (int j = 0; j < 4; ++j) {
                f32x4 lo = r.af[2 * j], hi = r.af[2 * j + 1];
                u32x4 u = { pack2(lo[0], lo[1]), pack2(lo[2], lo[3]),
                            pack2(hi[0], hi[1]), pack2(hi[2], hi[3]) };
                *(u32x4*)&sA[buf][arow + j * 32][c8] = u;
            }
        }
        #pragma unroll
        for (int j = 0; j < 4; ++j) {
            f32x4 lo = r.b[2 * j], hi = r.b[2 * j + 1];
            u32x4 u = { pack2(lo[0], lo[1]), pack2(lo[2], lo[3]),
                        pack2(hi[0], hi[1]), pack2(hi[2], hi[3]) };
            *(u32x4*)&sB[buf][arow + j * 32][c8] = u;
        }
    };

    auto COMPUTE = [&](int buf) {
        #pragma unroll
        for (int kh = 0; kh < 2; ++kh) {
            const int off = kh ? offk1 : offk0;
            bf16x8 af[4], bfr[4];
            #pragma unroll
            for (int i = 0; i < 4; ++i)
                af[i] = *(const bf16x8*)&sA[buf][wr * 64 + i * 16 + lrow][off];
            #pragma unroll
            for (int n = 0; n < 4; ++n)
                bfr[n] = *(const bf16x8*)&sB[buf][wc * 64 + n * 16 + lrow][off];
            #pragma unroll
            for (int i = 0; i < 4; ++i)
                #pragma unroll
                for (int n = 0; n < 4; ++n)
                    acc[i][n] = __builtin_amdgcn_mfma_f32_16x16x32_bf16(af[i], bfr[n], acc[i][n], 0, 0, 0);
        }
    };

    // Prologue: 2 tiles in flight.
    LOAD(0, r0);
    LOAD(1, r1);
    WRITE(0, r0);                          // counted vmcnt: waits only set 0
    asm volatile("s_waitcnt lgkmcnt(0)" ::: "memory");
    __builtin_amdgcn_s_barrier();

    for (int t = 0; t < NT; t += 2) {
        if (t + 2 < NT) LOAD(t + 2, r0);
        COMPUTE(0);
        if (t + 1 < NT) WRITE(1, r1);      // r0's newer loads stay in flight
        asm volatile("s_waitcnt lgkmcnt(0)" ::: "memory");
        __builtin_amdgcn_s_barrier();

        if (t + 3 < NT) LOAD(t + 3, r1);
        COMPUTE(1);
        if (t + 2 < NT) WRITE(0, r0);
        asm volatile("s_waitcnt lgkmcnt(0)" ::: "memory");
        __builtin_amdgcn_s_barrier();
    }

    // Epilogue. C/D layout (m89-verified): col = lane&15, row = (lane>>4)*4 + reg
    const size_t crow0 = (size_t)e * TOKS;
    if constexpr (RELU_OUT_BF16) {
        unsigned short* C = (unsigned short*)Cp;
        #pragma unroll
        for (int i = 0; i < 4; ++i)
            #pragma unroll
            for (int n = 0; n < 4; ++n)
                #pragma unroll
                for (int q = 0; q < 4; ++q) {
                    const int row = wr * 64 + i * 16 + kq * 4 + q;
                    const int col = nt * 128 + wc * 64 + n * 16 + lrow;
                    C[(crow0 + row) * N + col] = f2bf(fmaxf(acc[i][n][q], 0.f));
                }
    } else {
        float* C = (float*)Cp;
        #pragma unroll
        for (int i = 0; i < 4; ++i)
            #pragma unroll
            for (int n = 0; n < 4; ++n)
                #pragma unroll
                for (int q = 0; q < 4; ++q) {
                    const int row = wr * 64 + i * 16 + kq * 4 + q;
                    const int col = nt * 128 + wc * 64 + n * 16 + lrow;
                    C[(crow0 + row) * N + col] = acc[i][n][q];
                }
    }
}

extern "C" void kernel_launch(void* const* d_in, const int* in_sizes, int n_in,
                              void* d_out, int out_size, void* d_ws, size_t ws_size,
                              hipStream_t stream) {
    const float* inputs = (const float*)d_in[0];   // [8192, 1024] fp32
    const float* w1     = (const float*)d_in[1];   // [64, 4096, 1024] fp32
    const float* w2     = (const float*)d_in[2];   // [64, 1024, 4096] fp32
    // d_in[3] = splits (always 128) -- unused

    unsigned short* h = (unsigned short*)d_ws;     // [8192, 4096] bf16 = 64 MiB
    float* out = (float*)d_out;                    // [8192, 1024] fp32

    // Pass 1: h = relu(x @ w1^T), bf16; x staged fp32->bf16 inline. grid = 2048
    moe_gemm<DH, DM, false, true><<<dim3(N_EXPERTS * (DH / 128)), dim3(256), 0, stream>>>(
        inputs, w1, h, N_EXPERTS * (DH / 128) / 8);
    // Pass 2: out = h @ w2^T, fp32. grid = 512
    moe_gemm<DM, DH, true, false><<<dim3(N_EXPERTS * (DM / 128)), dim3(256), 0, stream>>>(
        h, w2, out, N_EXPERTS * (DM / 128) / 8);
}